// Round 8
// baseline (134.993 us; speedup 1.0000x reference)
//
#include <hip/hip_runtime.h>

typedef __attribute__((ext_vector_type(8))) short short8;
typedef __attribute__((ext_vector_type(4))) float f32x4;
typedef __attribute__((ext_vector_type(4))) unsigned int u32x4;
typedef unsigned short ushort_t;

constexpr int B   = 4;
constexpr int C   = 256;
constexpr int H   = 64;
constexpr int W   = 64;
constexpr int HW  = H * W;          // 4096
constexpr int OCH = 256;
constexpr int KT  = 9 * C;          // 2304, k order: k = tap*256 + c
constexpr int NHS = KT / 32;        // 72 half-steps (MFMA K=32)

__device__ __forceinline__ ushort_t f2bf(float f) {
    unsigned u = __float_as_uint(f);
    u += 0x7FFF + ((u >> 16) & 1);      // RNE
    return (ushort_t)(u >> 16);
}

// Barrier that does NOT drain vmcnt: LDS writes are made visible
// (lgkmcnt(0)), but in-register global loads stay in flight across it.
// Fences stop the compiler moving LDS ops across the barrier.
__device__ __forceinline__ void block_sync_lds() {
    asm volatile("s_waitcnt lgkmcnt(0)" ::: "memory");
    __builtin_amdgcn_s_barrier();
    asm volatile("" ::: "memory");
}

// ---------------------------------------------------------------------------
// K0: xtP[bl][y][x][c] (bf16) <- x[pbase+bl][c][y][x] (f32), bl in {0,1}.
// ---------------------------------------------------------------------------
__global__ __launch_bounds__(256) void transpose_pair(
    const float* __restrict__ x, ushort_t* __restrict__ xtP, int pbase)
{
    __shared__ float sT[64][65];
    int blk = blockIdx.x;            // 2*64*4 = 512
    int cg  = blk & 3;               // channel group of 64
    int y   = (blk >> 2) & 63;
    int bl  = blk >> 8;              // 0..1
    int b   = pbase + bl;
    int t   = threadIdx.x;
    int col = t & 63, r4 = t >> 6;

    const float* xp = x + (((size_t)b * C + cg * 64) * H + y) * W;
    #pragma unroll
    for (int i = 0; i < 16; ++i) {
        int cl = i * 4 + r4;
        sT[cl][col] = xp[(size_t)cl * HW + col];
    }
    __syncthreads();
    ushort_t* op = xtP + (((size_t)bl * H + y) * W) * C + cg * 64;
    #pragma unroll
    for (int i = 0; i < 16; ++i) {
        int xl = i * 4 + r4;
        op[(size_t)xl * C + col] = f2bf(sT[col][xl]);
    }
}

// ---------------------------------------------------------------------------
// K1: pack w_def into bf16 A-fragment order (validated rounds 2-7).
//   wPack[((ks*16 + gt)*64 + lane)*8 + j] = bf16(w_def[o][c][tap])
//   o = gt*16 + (lane&15);  k = ks*32 + (lane>>4)*8 + j; tap = k>>8; c = k&255
// ---------------------------------------------------------------------------
__global__ __launch_bounds__(256) void pack_w(
    const float* __restrict__ w_def, ushort_t* __restrict__ wPack)
{
    int tid = blockIdx.x * 256 + threadIdx.x;     // 72*16*64 = 73728
    if (tid >= NHS * 16 * 64) return;
    int lane = tid & 63;
    int o = ((tid >> 6) & 15) * 16 + (lane & 15);
    int kbase = (tid >> 10) * 32 + (lane >> 4) * 8;
    union { ushort_t u[8]; short8 v; } pk;
    #pragma unroll
    for (int j = 0; j < 8; ++j) {
        int kidx = kbase + j;
        int c = kidx & 255, tap = kidx >> 8;
        pk.u[j] = f2bf(w_def[((size_t)o * C + c) * 9 + tap]);
    }
    *(short8*)(wPack + (size_t)tid * 8) = pk.v;
}

// ---------------------------------------------------------------------------
// K2: pack w_off into bf16 A-fragment order, M padded 18 -> 32.
// ---------------------------------------------------------------------------
__global__ __launch_bounds__(256) void pack_woffA(
    const float* __restrict__ w_off, ushort_t* __restrict__ wOffA)
{
    int tid = blockIdx.x * 256 + threadIdx.x;     // 72*2*64 = 9216
    if (tid >= NHS * 2 * 64) return;
    int lane = tid & 63;
    int o = ((tid >> 6) & 1) * 16 + (lane & 15);
    int kbase = (tid >> 7) * 32 + (lane >> 4) * 8;
    union { ushort_t u[8]; short8 v; } pk;
    #pragma unroll
    for (int j = 0; j < 8; ++j) {
        int kidx = kbase + j;
        int c = kidx & 255, tap = kidx >> 8;
        pk.u[j] = (o < 18) ? f2bf(w_off[((size_t)o * C + c) * 9 + tap]) : (ushort_t)0;
    }
    *(short8*)(wOffA + (size_t)tid * 8) = pk.v;
}

// ---------------------------------------------------------------------------
// K3: offset conv via MFMA (validated rounds 5-7).  Grid (bl,ho,kg) = 256.
// ---------------------------------------------------------------------------
__global__ __launch_bounds__(256) void offconv_mfma(
    const ushort_t* __restrict__ xtP, const ushort_t* __restrict__ wOffA,
    float* __restrict__ offPart)
{
    int orig = blockIdx.x;
    int r = ((orig & 7) << 5) | (orig >> 3);   // XCD swizzle, 256 blocks
    int bl = r >> 7, ho = (r >> 1) & 63, kg = r & 1;
    int tid = threadIdx.x;
    int lane = tid & 63, wv = tid >> 6;
    int px = wv * 16 + (lane & 15);
    int cseg = (lane >> 4) * 8;

    const ushort_t* xtb = xtP + (size_t)bl * HW * C;
    const short8*   wA  = (const short8*)wOffA;

    f32x4 acc[2];
    acc[0] = (f32x4){0.f, 0.f, 0.f, 0.f};
    acc[1] = (f32x4){0.f, 0.f, 0.f, 0.f};

    int tap0 = kg ? 4 : 0;
    int tap1 = kg ? 9 : 4;

    #pragma unroll 1
    for (int tap = tap0; tap < tap1; ++tap) {
        int ky = tap / 3, kx = tap - ky * 3;
        int y  = ho - 1 + ky;
        int xx = px - 1 + kx;
        bool ok = ((unsigned)y < 64u) && ((unsigned)xx < 64u);
        unsigned msk = ok ? 0xffffffffu : 0u;
        int yc = min(max(y, 0), 63), xc = min(max(xx, 0), 63);
        const ushort_t* srcb = xtb + (size_t)(yc * 64 + xc) * C + cseg;

        #pragma unroll
        for (int cs = 0; cs < 8; ++cs) {
            union { u32x4 u; short8 s; } bv;
            bv.u = *(const u32x4*)(srcb + cs * 32);
            bv.u[0] &= msk; bv.u[1] &= msk; bv.u[2] &= msk; bv.u[3] &= msk;
            int ks = tap * 8 + cs;
            short8 aF0 = wA[(size_t)ks * 128 + lane];
            short8 aF1 = wA[(size_t)ks * 128 + 64 + lane];
            acc[0] = __builtin_amdgcn_mfma_f32_16x16x32_bf16(aF0, bv.s, acc[0], 0, 0, 0);
            acc[1] = __builtin_amdgcn_mfma_f32_16x16x32_bf16(aF1, bv.s, acc[1], 0, 0, 0);
        }
    }

    #pragma unroll
    for (int gt = 0; gt < 2; ++gt) {
        #pragma unroll
        for (int j = 0; j < 4; ++j) {
            int oc = gt * 16 + (lane >> 4) * 4 + j;
            if (oc < 18)
                offPart[(((size_t)kg * 2 + bl) * 18 + oc) * HW + ho * 64 + px] = acc[gt][j];
        }
    }
}

// ---------------------------------------------------------------------------
// K4: bilinear sample + bf16 MFMA GEMM, depth-2 pipelined, NON-DRAINING
// barriers (raw s_barrier + lgkmcnt(0) only): gathers issued after barrier N
// stay in flight across barrier N+1, consumed at blend N+2.
// Grid (bl,ho,ohalf,pxh) = 512 blocks x 256 thr (2 blocks/CU).
// ---------------------------------------------------------------------------
__global__ __launch_bounds__(256, 2) void deform_pair(
    const ushort_t* __restrict__ xtP, const float* __restrict__ offPart,
    const ushort_t* __restrict__ wPack, float* __restrict__ out, int pbase)
{
    __shared__ __align__(16) ushort_t sS[2][16][33][8];  // 16.9 KB
    __shared__ float sOff[18][32];                       // 2.3 KB

    int orig = blockIdx.x;
    int r = ((orig & 7) << 6) | (orig >> 3);   // XCD swizzle, 512 blocks
    int bl = r >> 8, ho = (r >> 2) & 63, ohalf = (r >> 1) & 1, pxh = r & 1;
    int tid = threadIdx.x;
    int lane = tid & 63, wv = tid >> 6;        // 4 waves
    int px32 = tid & 31, kc = tid >> 5;        // staging identity, kc in [0,8)
    int px = pxh * 32 + px32;

    const ushort_t* xtb = xtP + (size_t)bl * HW * C;

    // this row's offsets for our px half (sum of the two K-split partials)
    for (int idx = tid; idx < 18 * 32; idx += 256) {
        int oc = idx >> 5, p2 = idx & 31;
        size_t base = ((size_t)bl * 18 + oc) * HW + ho * 64 + pxh * 32 + p2;
        sOff[oc][p2] = offPart[base] + offPart[(size_t)2 * 18 * HW + base];
    }
    __syncthreads();

    f32x4 acc2[2][2];
    #pragma unroll
    for (int i = 0; i < 2; ++i)
        #pragma unroll
        for (int j = 0; j < 2; ++j) acc2[i][j] = (f32x4){0.f, 0.f, 0.f, 0.f};

    // two param sets: A = current tap (blend weights), B = next tap (issue addrs)
    float wA0, wA1, wA2, wA3;  int oA0, oA1, oA2, oA3;
    float wB0, wB1, wB2, wB3;  int oB0, oB1, oB2, oB3;

    auto mk = [&](int tap, float& w00, float& w01, float& w10, float& w11,
                  int& o00, int& o01, int& o10, int& o11) {
        int ky = tap / 3, kx = tap - ky * 3;
        float offy = sOff[2 * tap][px32];
        float offx = sOff[2 * tap + 1][px32];
        float py  = offy + (float)(ho - 1 + ky);
        float pxf = offx + (float)(px - 1 + kx);
        float y0f = floorf(py), x0f = floorf(pxf);
        float wy1 = py - y0f, wx1 = pxf - x0f;
        float wy0 = 1.f - wy1, wx0 = 1.f - wx1;
        int y0 = (int)y0f, x0 = (int)x0f;
        int y1 = y0 + 1, x1 = x0 + 1;
        float vy0 = ((unsigned)y0 < 64u) ? 1.f : 0.f;
        float vy1 = ((unsigned)y1 < 64u) ? 1.f : 0.f;
        float vx0 = ((unsigned)x0 < 64u) ? 1.f : 0.f;
        float vx1 = ((unsigned)x1 < 64u) ? 1.f : 0.f;
        int y0c = min(max(y0, 0), 63), y1c = min(max(y1, 0), 63);
        int x0c = min(max(x0, 0), 63), x1c = min(max(x1, 0), 63);
        o00 = (y0c * 64 + x0c) * C; o01 = (y0c * 64 + x1c) * C;
        o10 = (y1c * 64 + x0c) * C; o11 = (y1c * 64 + x1c) * C;
        w00 = wy0 * wx0 * vy0 * vx0; w01 = wy0 * wx1 * vy0 * vx1;
        w10 = wy1 * wx0 * vy1 * vx0; w11 = wy1 * wx1 * vy1 * vx1;
    };

    // gather slots kc (c0 = sub*128 + kc*8) and kc+8 (c0+64): 8 x 16B loads
    auto issue8 = [&](int sub, int o00, int o01, int o10, int o11, u32x4* L) {
        const ushort_t* p = xtb + sub * 128 + kc * 8;
        L[0] = *(const u32x4*)(p + o00);
        L[1] = *(const u32x4*)(p + o01);
        L[2] = *(const u32x4*)(p + o10);
        L[3] = *(const u32x4*)(p + o11);
        const ushort_t* p2 = p + 64;
        L[4] = *(const u32x4*)(p2 + o00);
        L[5] = *(const u32x4*)(p2 + o01);
        L[6] = *(const u32x4*)(p2 + o10);
        L[7] = *(const u32x4*)(p2 + o11);
    };

    auto blend2 = [&](const u32x4* L, float w00, float w01, float w10, float w11, int p) {
        #pragma unroll
        for (int q = 0; q < 2; ++q) {
            unsigned pk[4];
            #pragma unroll
            for (int j = 0; j < 4; ++j) {
                float f0l = __uint_as_float(L[q * 4 + 0][j] << 16);
                float f0h = __uint_as_float(L[q * 4 + 0][j] & 0xffff0000u);
                float f1l = __uint_as_float(L[q * 4 + 1][j] << 16);
                float f1h = __uint_as_float(L[q * 4 + 1][j] & 0xffff0000u);
                float f2l = __uint_as_float(L[q * 4 + 2][j] << 16);
                float f2h = __uint_as_float(L[q * 4 + 2][j] & 0xffff0000u);
                float f3l = __uint_as_float(L[q * 4 + 3][j] << 16);
                float f3h = __uint_as_float(L[q * 4 + 3][j] & 0xffff0000u);
                float lo = fmaf(w00, f0l, fmaf(w01, f1l, fmaf(w10, f2l, w11 * f3l)));
                float hi = fmaf(w00, f0h, fmaf(w01, f1h, fmaf(w10, f2h, w11 * f3h)));
                asm("v_cvt_pk_bf16_f32 %0, %1, %2" : "=v"(pk[j]) : "v"(lo), "v"(hi));
            }
            u32x4 wvec = (u32x4){pk[0], pk[1], pk[2], pk[3]};
            *(u32x4*)&sS[p][kc + q * 8][px32][0] = wvec;
        }
    };

    int gt0 = ohalf * 8 + wv * 2;
    const short8* wpB = (const short8*)wPack;

    auto loadA = [&](int ks4base, short8* A) {   // 8 A-frags for one sub
        #pragma unroll
        for (int h = 0; h < 4; ++h) {
            size_t an = ((size_t)(ks4base + h) * 16 + gt0) * 64 + lane;
            A[2 * h]     = wpB[an];
            A[2 * h + 1] = wpB[an + 64];
        }
    };

    auto mfmaPhase = [&](const short8* A, int p) {
        #pragma unroll
        for (int h = 0; h < 4; ++h) {
            #pragma unroll
            for (int pt = 0; pt < 2; ++pt) {
                short8 bF = *(const short8*)&sS[p][h * 4 + (lane >> 4)][pt * 16 + (lane & 15)][0];
                acc2[0][pt] = __builtin_amdgcn_mfma_f32_16x16x32_bf16(A[2 * h],     bF, acc2[0][pt], 0, 0, 0);
                acc2[1][pt] = __builtin_amdgcn_mfma_f32_16x16x32_bf16(A[2 * h + 1], bF, acc2[1][pt], 0, 0, 0);
            }
        }
    };

    u32x4 LA[8], LB[8];
    short8 A0[8], A1[8];

    mk(0, wA0, wA1, wA2, wA3, oA0, oA1, oA2, oA3);
    issue8(0, oA0, oA1, oA2, oA3, LA);
    issue8(1, oA0, oA1, oA2, oA3, LB);
    loadA(0, A0);

    int p = 0;
    #pragma unroll 1
    for (int tap = 0; tap < 9; ++tap) {
        if (tap < 8) mk(tap + 1, wB0, wB1, wB2, wB3, oB0, oB1, oB2, oB3);

        // ---- sub 0 ----
        blend2(LA, wA0, wA1, wA2, wA3, p);
        block_sync_lds();                                  // non-draining
        if (tap < 8) issue8(0, oB0, oB1, oB2, oB3, LA);   // next tap, sub 0
        loadA(tap * 8 + 4, A1);                            // A-frags for sub 1
        mfmaPhase(A0, p);
        p ^= 1;

        // ---- sub 1 ----
        blend2(LB, wA0, wA1, wA2, wA3, p);
        block_sync_lds();                                  // non-draining
        if (tap < 8) {
            issue8(1, oB0, oB1, oB2, oB3, LB);             // next tap, sub 1
            loadA((tap + 1) * 8, A0);                      // next tap, sub 0
        }
        mfmaPhase(A1, p);
        p ^= 1;

        // promote params (next tap becomes current)
        wA0 = wB0; wA1 = wB1; wA2 = wB2; wA3 = wB3;
        oA0 = oB0; oA1 = oB1; oA2 = oB2; oA3 = oB3;
    }

    // epilogue: D[row=(l>>4)*4+j][col=l&15]
    int b = pbase + bl;
    #pragma unroll
    for (int ot = 0; ot < 2; ++ot) {
        int o = ohalf * 128 + wv * 32 + ot * 16 + (lane >> 4) * 4;
        #pragma unroll
        for (int pt = 0; pt < 2; ++pt) {
            int pxx = pxh * 32 + pt * 16 + (lane & 15);
            #pragma unroll
            for (int j = 0; j < 4; ++j)
                out[(((size_t)b * OCH + (o + j)) * H + ho) * W + pxx] = acc2[ot][pt][j];
        }
    }
}

// ---------------------------------------------------------------------------
extern "C" void kernel_launch(void* const* d_in, const int* in_sizes, int n_in,
                              void* d_out, int out_size, void* d_ws, size_t ws_size,
                              hipStream_t stream)
{
    const float* x     = (const float*)d_in[0];
    const float* w_off = (const float*)d_in[1];
    const float* w_def = (const float*)d_in[2];
    float* out = (float*)d_out;

    // ws: xtPair[4.19MB] | wPack[1.18MB] | wOffA[147KB] | offPart[1.18MB]
    // total 6,701,056 B  (< round-2-proven 7,077,888 B budget)
    ushort_t* xtP     = (ushort_t*)d_ws;
    ushort_t* wPack   = xtP + (size_t)2 * HW * C;
    ushort_t* wOffA   = wPack + (size_t)NHS * 16 * 64 * 8;
    float*    offPart = (float*)(wOffA + (size_t)NHS * 2 * 64 * 8);

    pack_w<<<(NHS * 16 * 64 + 255) / 256, 256, 0, stream>>>(w_def, wPack);
    pack_woffA<<<(NHS * 2 * 64 + 255) / 256, 256, 0, stream>>>(w_off, wOffA);

    for (int pr = 0; pr < 2; ++pr) {
        transpose_pair<<<512, 256, 0, stream>>>(x, xtP, pr * 2);
        offconv_mfma<<<256, 256, 0, stream>>>(xtP, wOffA, offPart);
        deform_pair<<<512, 256, 0, stream>>>(xtP, offPart, wPack, out, pr * 2);
    }
}

// Round 9
// 114.127 us; speedup vs baseline: 1.1828x; 1.1828x over previous
//
#include <hip/hip_runtime.h>

typedef __attribute__((ext_vector_type(8))) short short8;
typedef __attribute__((ext_vector_type(4))) float f32x4;
typedef __attribute__((ext_vector_type(4))) unsigned int u32x4;
typedef unsigned short ushort_t;

constexpr int B   = 4;
constexpr int C   = 256;
constexpr int H   = 64;
constexpr int W   = 64;
constexpr int HW  = H * W;          // 4096
constexpr int OCH = 256;
constexpr int KT  = 9 * C;          // 2304, k order: k = tap*256 + c
constexpr int NHS = KT / 32;        // 72 half-steps (MFMA K=32)

__device__ __forceinline__ ushort_t f2bf(float f) {
    unsigned u = __float_as_uint(f);
    u += 0x7FFF + ((u >> 16) & 1);      // RNE
    return (ushort_t)(u >> 16);
}

// Barrier that does NOT drain vmcnt: LDS writes are made visible
// (lgkmcnt(0)), but in-register global loads stay in flight across it.
__device__ __forceinline__ void block_sync_lds() {
    asm volatile("s_waitcnt lgkmcnt(0)" ::: "memory");
    __builtin_amdgcn_s_barrier();
    asm volatile("" ::: "memory");
}

// ---------------------------------------------------------------------------
// K0: xtP[bl][y][x][c] (bf16) <- x[pbase+bl][c][y][x] (f32), bl in {0,1}.
// ---------------------------------------------------------------------------
__global__ __launch_bounds__(256) void transpose_pair(
    const float* __restrict__ x, ushort_t* __restrict__ xtP, int pbase)
{
    __shared__ float sT[64][65];
    int blk = blockIdx.x;            // 2*64*4 = 512
    int cg  = blk & 3;               // channel group of 64
    int y   = (blk >> 2) & 63;
    int bl  = blk >> 8;              // 0..1
    int b   = pbase + bl;
    int t   = threadIdx.x;
    int col = t & 63, r4 = t >> 6;

    const float* xp = x + (((size_t)b * C + cg * 64) * H + y) * W;
    #pragma unroll
    for (int i = 0; i < 16; ++i) {
        int cl = i * 4 + r4;
        sT[cl][col] = xp[(size_t)cl * HW + col];
    }
    __syncthreads();
    ushort_t* op = xtP + (((size_t)bl * H + y) * W) * C + cg * 64;
    #pragma unroll
    for (int i = 0; i < 16; ++i) {
        int xl = i * 4 + r4;
        op[(size_t)xl * C + col] = f2bf(sT[col][xl]);
    }
}

// ---------------------------------------------------------------------------
// K1: pack w_def into bf16 A-fragment order (validated rounds 2-8).
// ---------------------------------------------------------------------------
__global__ __launch_bounds__(256) void pack_w(
    const float* __restrict__ w_def, ushort_t* __restrict__ wPack)
{
    int tid = blockIdx.x * 256 + threadIdx.x;     // 72*16*64 = 73728
    if (tid >= NHS * 16 * 64) return;
    int lane = tid & 63;
    int o = ((tid >> 6) & 15) * 16 + (lane & 15);
    int kbase = (tid >> 10) * 32 + (lane >> 4) * 8;
    union { ushort_t u[8]; short8 v; } pk;
    #pragma unroll
    for (int j = 0; j < 8; ++j) {
        int kidx = kbase + j;
        int c = kidx & 255, tap = kidx >> 8;
        pk.u[j] = f2bf(w_def[((size_t)o * C + c) * 9 + tap]);
    }
    *(short8*)(wPack + (size_t)tid * 8) = pk.v;
}

// ---------------------------------------------------------------------------
// K2: pack w_off into bf16 A-fragment order, M padded 18 -> 32.
// ---------------------------------------------------------------------------
__global__ __launch_bounds__(256) void pack_woffA(
    const float* __restrict__ w_off, ushort_t* __restrict__ wOffA)
{
    int tid = blockIdx.x * 256 + threadIdx.x;     // 72*2*64 = 9216
    if (tid >= NHS * 2 * 64) return;
    int lane = tid & 63;
    int o = ((tid >> 6) & 1) * 16 + (lane & 15);
    int kbase = (tid >> 7) * 32 + (lane >> 4) * 8;
    union { ushort_t u[8]; short8 v; } pk;
    #pragma unroll
    for (int j = 0; j < 8; ++j) {
        int kidx = kbase + j;
        int c = kidx & 255, tap = kidx >> 8;
        pk.u[j] = (o < 18) ? f2bf(w_off[((size_t)o * C + c) * 9 + tap]) : (ushort_t)0;
    }
    *(short8*)(wOffA + (size_t)tid * 8) = pk.v;
}

// ---------------------------------------------------------------------------
// K3: offset conv via MFMA (validated rounds 5-8).  Grid (bl,ho,kg) = 256.
// ---------------------------------------------------------------------------
__global__ __launch_bounds__(256) void offconv_mfma(
    const ushort_t* __restrict__ xtP, const ushort_t* __restrict__ wOffA,
    float* __restrict__ offPart)
{
    int orig = blockIdx.x;
    int r = ((orig & 7) << 5) | (orig >> 3);   // XCD swizzle, 256 blocks
    int bl = r >> 7, ho = (r >> 1) & 63, kg = r & 1;
    int tid = threadIdx.x;
    int lane = tid & 63, wv = tid >> 6;
    int px = wv * 16 + (lane & 15);
    int cseg = (lane >> 4) * 8;

    const ushort_t* xtb = xtP + (size_t)bl * HW * C;
    const short8*   wA  = (const short8*)wOffA;

    f32x4 acc[2];
    acc[0] = (f32x4){0.f, 0.f, 0.f, 0.f};
    acc[1] = (f32x4){0.f, 0.f, 0.f, 0.f};

    int tap0 = kg ? 4 : 0;
    int tap1 = kg ? 9 : 4;

    #pragma unroll 1
    for (int tap = tap0; tap < tap1; ++tap) {
        int ky = tap / 3, kx = tap - ky * 3;
        int y  = ho - 1 + ky;
        int xx = px - 1 + kx;
        bool ok = ((unsigned)y < 64u) && ((unsigned)xx < 64u);
        unsigned msk = ok ? 0xffffffffu : 0u;
        int yc = min(max(y, 0), 63), xc = min(max(xx, 0), 63);
        const ushort_t* srcb = xtb + (size_t)(yc * 64 + xc) * C + cseg;

        #pragma unroll
        for (int cs = 0; cs < 8; ++cs) {
            union { u32x4 u; short8 s; } bv;
            bv.u = *(const u32x4*)(srcb + cs * 32);
            bv.u[0] &= msk; bv.u[1] &= msk; bv.u[2] &= msk; bv.u[3] &= msk;
            int ks = tap * 8 + cs;
            short8 aF0 = wA[(size_t)ks * 128 + lane];
            short8 aF1 = wA[(size_t)ks * 128 + 64 + lane];
            acc[0] = __builtin_amdgcn_mfma_f32_16x16x32_bf16(aF0, bv.s, acc[0], 0, 0, 0);
            acc[1] = __builtin_amdgcn_mfma_f32_16x16x32_bf16(aF1, bv.s, acc[1], 0, 0, 0);
        }
    }

    #pragma unroll
    for (int gt = 0; gt < 2; ++gt) {
        #pragma unroll
        for (int j = 0; j < 4; ++j) {
            int oc = gt * 16 + (lane >> 4) * 4 + j;
            if (oc < 18)
                offPart[(((size_t)kg * 2 + bl) * 18 + oc) * HW + ho * 64 + px] = acc[gt][j];
        }
    }
}

// ---------------------------------------------------------------------------
// K4: bilinear sample + bf16 MFMA GEMM, COALESCED gathers.
// Per (tap,sub): 128 pixel-runs (4 nbr x 32 px) of 128 contiguous channels
// (256B).  Run bases precomputed into sBase (from sOff).  Loads: 16 lanes
// cover one run (16B/lane, coalesced), parked in regs one tap ahead, then
// ds_written to sRaw (272B run stride: bank-quad conflict-free).  Blend
// threads read their 4 neighbor chunks from sRaw; rest identical to r7/r8.
// Grid (bl,ho,ohalf,pxh) = 512 blocks x 256 thr (2 blocks/CU).
// ---------------------------------------------------------------------------
__global__ __launch_bounds__(256, 2) void deform_pair(
    const ushort_t* __restrict__ xtP, const float* __restrict__ offPart,
    const ushort_t* __restrict__ wPack, float* __restrict__ out, int pbase)
{
    __shared__ __align__(16) ushort_t sS[2][16][33][8];  // 16.9 KB
    __shared__ __align__(16) ushort_t sRaw[128 * 136];   // 34.8 KB, stride 272B
    __shared__ float sOff[18][32];                       // 2.3 KB
    __shared__ int   sBase[128];                         // run -> elem offset

    int orig = blockIdx.x;
    int r = ((orig & 7) << 6) | (orig >> 3);   // XCD swizzle, 512 blocks
    int bl = r >> 8, ho = (r >> 2) & 63, ohalf = (r >> 1) & 1, pxh = r & 1;
    int tid = threadIdx.x;
    int lane = tid & 63, wv = tid >> 6;        // 4 waves
    int px32 = tid & 31, kc = tid >> 5;        // blend identity
    int chunk = tid & 15, rq = tid >> 4;       // staging identity
    int px = pxh * 32 + px32;

    const ushort_t* xtb = xtP + (size_t)bl * HW * C;

    // this row's offsets for our px half (sum of the two K-split partials)
    for (int idx = tid; idx < 18 * 32; idx += 256) {
        int oc = idx >> 5, p2 = idx & 31;
        size_t base = ((size_t)bl * 18 + oc) * HW + ho * 64 + pxh * 32 + p2;
        sOff[oc][p2] = offPart[base] + offPart[(size_t)2 * 18 * HW + base];
    }
    __syncthreads();

    f32x4 acc2[2][2];
    #pragma unroll
    for (int i = 0; i < 2; ++i)
        #pragma unroll
        for (int j = 0; j < 2; ++j) acc2[i][j] = (f32x4){0.f, 0.f, 0.f, 0.f};

    // weights: A = current tap (blend), B = next tap
    float wA0, wA1, wA2, wA3, wB0, wB1, wB2, wB3;

    auto mkW = [&](int tap, float& w00, float& w01, float& w10, float& w11) {
        int ky = tap / 3, kx = tap - ky * 3;
        float offy = sOff[2 * tap][px32];
        float offx = sOff[2 * tap + 1][px32];
        float py  = offy + (float)(ho - 1 + ky);
        float pxf = offx + (float)(px - 1 + kx);
        float y0f = floorf(py), x0f = floorf(pxf);
        float wy1 = py - y0f, wx1 = pxf - x0f;
        float wy0 = 1.f - wy1, wx0 = 1.f - wx1;
        int y0 = (int)y0f, x0 = (int)x0f;
        int y1 = y0 + 1, x1 = x0 + 1;
        float vy0 = ((unsigned)y0 < 64u) ? 1.f : 0.f;
        float vy1 = ((unsigned)y1 < 64u) ? 1.f : 0.f;
        float vx0 = ((unsigned)x0 < 64u) ? 1.f : 0.f;
        float vx1 = ((unsigned)x1 < 64u) ? 1.f : 0.f;
        w00 = wy0 * wx0 * vy0 * vx0; w01 = wy0 * wx1 * vy0 * vx1;
        w10 = wy1 * wx0 * vy1 * vx0; w11 = wy1 * wx1 * vy1 * vx1;
    };

    // run r = n*32+q bases (clamped pixel * C), threads 0..127
    auto computeBase = [&](int tap) {
        if (tid < 128) {
            int n = tid >> 5, q = tid & 31;
            int ky = tap / 3, kx = tap - ky * 3;
            float offy = sOff[2 * tap][q];
            float offx = sOff[2 * tap + 1][q];
            float py  = offy + (float)(ho - 1 + ky);
            float pxf = offx + (float)(pxh * 32 + q - 1 + kx);
            int y0 = (int)floorf(py), x0 = (int)floorf(pxf);
            int yy = y0 + (n >> 1), xx = x0 + (n & 1);
            yy = min(max(yy, 0), 63); xx = min(max(xx, 0), 63);
            sBase[tid] = (yy * 64 + xx) * C;
        }
    };

    auto loadBases = [&](int* rb) {
        #pragma unroll
        for (int i = 0; i < 8; ++i) rb[i] = sBase[i * 16 + rq];
    };

    // coalesced: 8 x 16B, run i*16+rq, channels sub*128 + chunk*8 ..
    auto issueC = [&](const int* rb, int sub, u32x4* L) {
        #pragma unroll
        for (int i = 0; i < 8; ++i)
            L[i] = *(const u32x4*)(xtb + rb[i] + sub * 128 + chunk * 8);
    };

    auto rawWrite = [&](const u32x4* L) {
        #pragma unroll
        for (int i = 0; i < 8; ++i)
            *(u32x4*)&sRaw[(i * 16 + rq) * 136 + chunk * 8] = L[i];
    };

    auto blendFromRaw = [&](float w00, float w01, float w10, float w11, int p) {
        #pragma unroll
        for (int q2 = 0; q2 < 2; ++q2) {
            int ch = kc + q2 * 8;
            u32x4 Ln[4];
            #pragma unroll
            for (int n = 0; n < 4; ++n)
                Ln[n] = *(const u32x4*)&sRaw[(n * 32 + px32) * 136 + ch * 8];
            unsigned pk[4];
            #pragma unroll
            for (int j = 0; j < 4; ++j) {
                float f0l = __uint_as_float(Ln[0][j] << 16);
                float f0h = __uint_as_float(Ln[0][j] & 0xffff0000u);
                float f1l = __uint_as_float(Ln[1][j] << 16);
                float f1h = __uint_as_float(Ln[1][j] & 0xffff0000u);
                float f2l = __uint_as_float(Ln[2][j] << 16);
                float f2h = __uint_as_float(Ln[2][j] & 0xffff0000u);
                float f3l = __uint_as_float(Ln[3][j] << 16);
                float f3h = __uint_as_float(Ln[3][j] & 0xffff0000u);
                float lo = fmaf(w00, f0l, fmaf(w01, f1l, fmaf(w10, f2l, w11 * f3l)));
                float hi = fmaf(w00, f0h, fmaf(w01, f1h, fmaf(w10, f2h, w11 * f3h)));
                asm("v_cvt_pk_bf16_f32 %0, %1, %2" : "=v"(pk[j]) : "v"(lo), "v"(hi));
            }
            u32x4 wvec = (u32x4){pk[0], pk[1], pk[2], pk[3]};
            *(u32x4*)&sS[p][kc + q2 * 8][px32][0] = wvec;
        }
    };

    int gt0 = ohalf * 8 + wv * 2;
    const short8* wpB = (const short8*)wPack;

    auto loadA = [&](int ks4base, short8* A) {   // 8 A-frags for one sub
        #pragma unroll
        for (int h = 0; h < 4; ++h) {
            size_t an = ((size_t)(ks4base + h) * 16 + gt0) * 64 + lane;
            A[2 * h]     = wpB[an];
            A[2 * h + 1] = wpB[an + 64];
        }
    };

    auto mfmaPhase = [&](const short8* A, int p) {
        #pragma unroll
        for (int h = 0; h < 4; ++h) {
            #pragma unroll
            for (int pt = 0; pt < 2; ++pt) {
                short8 bF = *(const short8*)&sS[p][h * 4 + (lane >> 4)][pt * 16 + (lane & 15)][0];
                acc2[0][pt] = __builtin_amdgcn_mfma_f32_16x16x32_bf16(A[2 * h],     bF, acc2[0][pt], 0, 0, 0);
                acc2[1][pt] = __builtin_amdgcn_mfma_f32_16x16x32_bf16(A[2 * h + 1], bF, acc2[1][pt], 0, 0, 0);
            }
        }
    };

    u32x4 LA[8], LB[8];
    short8 A0[8], A1[8];

    // prologue
    computeBase(0);
    block_sync_lds();
    {
        int rbP[8];
        loadBases(rbP);
        issueC(rbP, 0, LA);
        issueC(rbP, 1, LB);
    }
    loadA(0, A0);
    mkW(0, wA0, wA1, wA2, wA3);

    int p = 0;
    #pragma unroll 1
    for (int tap = 0; tap < 9; ++tap) {
        if (tap < 8) {
            mkW(tap + 1, wB0, wB1, wB2, wB3);
            computeBase(tap + 1);                       // published at next barrier
        }
        int rb[8];
        // ---- sub 0 ----
        rawWrite(LA);
        block_sync_lds();                               // raw + sBase visible
        if (tap < 8) { loadBases(rb); issueC(rb, 0, LA); }   // next tap, in-flight
        blendFromRaw(wA0, wA1, wA2, wA3, p);
        loadA(tap * 8 + 4, A1);
        block_sync_lds();                               // sS[p] visible; raw reads done
        mfmaPhase(A0, p);
        p ^= 1;
        // ---- sub 1 ----
        rawWrite(LB);
        block_sync_lds();
        if (tap < 8) { issueC(rb, 1, LB); loadA((tap + 1) * 8, A0); }
        blendFromRaw(wA0, wA1, wA2, wA3, p);
        block_sync_lds();
        mfmaPhase(A1, p);
        p ^= 1;

        wA0 = wB0; wA1 = wB1; wA2 = wB2; wA3 = wB3;
    }

    // epilogue: D[row=(l>>4)*4+j][col=l&15]
    int b = pbase + bl;
    #pragma unroll
    for (int ot = 0; ot < 2; ++ot) {
        int o = ohalf * 128 + wv * 32 + ot * 16 + (lane >> 4) * 4;
        #pragma unroll
        for (int pt = 0; pt < 2; ++pt) {
            int pxx = pxh * 32 + pt * 16 + (lane & 15);
            #pragma unroll
            for (int j = 0; j < 4; ++j)
                out[(((size_t)b * OCH + (o + j)) * H + ho) * W + pxx] = acc2[ot][pt][j];
        }
    }
}

// ---------------------------------------------------------------------------
extern "C" void kernel_launch(void* const* d_in, const int* in_sizes, int n_in,
                              void* d_out, int out_size, void* d_ws, size_t ws_size,
                              hipStream_t stream)
{
    const float* x     = (const float*)d_in[0];
    const float* w_off = (const float*)d_in[1];
    const float* w_def = (const float*)d_in[2];
    float* out = (float*)d_out;

    // ws: xtPair[4.19MB] | wPack[1.18MB] | wOffA[147KB] | offPart[1.18MB]
    ushort_t* xtP     = (ushort_t*)d_ws;
    ushort_t* wPack   = xtP + (size_t)2 * HW * C;
    ushort_t* wOffA   = wPack + (size_t)NHS * 16 * 64 * 8;
    float*    offPart = (float*)(wOffA + (size_t)NHS * 2 * 64 * 8);

    pack_w<<<(NHS * 16 * 64 + 255) / 256, 256, 0, stream>>>(w_def, wPack);
    pack_woffA<<<(NHS * 2 * 64 + 255) / 256, 256, 0, stream>>>(w_off, wOffA);

    for (int pr = 0; pr < 2; ++pr) {
        transpose_pair<<<512, 256, 0, stream>>>(x, xtP, pr * 2);
        offconv_mfma<<<256, 256, 0, stream>>>(xtP, wOffA, offPart);
        deform_pair<<<512, 256, 0, stream>>>(xtP, offPart, wPack, out, pr * 2);
    }
}

// Round 10
// 103.267 us; speedup vs baseline: 1.3072x; 1.1052x over previous
//
#include <hip/hip_runtime.h>

typedef __attribute__((ext_vector_type(8))) short short8;
typedef __attribute__((ext_vector_type(4))) float f32x4;
typedef __attribute__((ext_vector_type(4))) unsigned int u32x4;
typedef unsigned short ushort_t;

constexpr int B   = 4;
constexpr int C   = 256;
constexpr int H   = 64;
constexpr int W   = 64;
constexpr int HW  = H * W;          // 4096
constexpr int OCH = 256;
constexpr int KT  = 9 * C;          // 2304, k order: k = tap*256 + c
constexpr int NHS = KT / 32;        // 72 half-steps (MFMA K=32)

__device__ __forceinline__ ushort_t f2bf(float f) {
    unsigned u = __float_as_uint(f);
    u += 0x7FFF + ((u >> 16) & 1);      // RNE
    return (ushort_t)(u >> 16);
}

// Barrier that does NOT drain vmcnt: LDS writes are made visible
// (lgkmcnt(0)), but in-register global loads stay in flight across it.
__device__ __forceinline__ void block_sync_lds() {
    asm volatile("s_waitcnt lgkmcnt(0)" ::: "memory");
    __builtin_amdgcn_s_barrier();
    asm volatile("" ::: "memory");
}

// ---------------------------------------------------------------------------
// K0: xtP[bl][y][x][c] (bf16) <- x[pbase+bl][c][y][x] (f32), bl in {0,1}.
// ---------------------------------------------------------------------------
__global__ __launch_bounds__(256) void transpose_pair(
    const float* __restrict__ x, ushort_t* __restrict__ xtP, int pbase)
{
    __shared__ float sT[64][65];
    int blk = blockIdx.x;            // 2*64*4 = 512
    int cg  = blk & 3;               // channel group of 64
    int y   = (blk >> 2) & 63;
    int bl  = blk >> 8;              // 0..1
    int b   = pbase + bl;
    int t   = threadIdx.x;
    int col = t & 63, r4 = t >> 6;

    const float* xp = x + (((size_t)b * C + cg * 64) * H + y) * W;
    #pragma unroll
    for (int i = 0; i < 16; ++i) {
        int cl = i * 4 + r4;
        sT[cl][col] = xp[(size_t)cl * HW + col];
    }
    __syncthreads();
    ushort_t* op = xtP + (((size_t)bl * H + y) * W) * C + cg * 64;
    #pragma unroll
    for (int i = 0; i < 16; ++i) {
        int xl = i * 4 + r4;
        op[(size_t)xl * C + col] = f2bf(sT[col][xl]);
    }
}

// ---------------------------------------------------------------------------
// K1: pack w_def into bf16 A-fragment order (validated rounds 2-9).
// ---------------------------------------------------------------------------
__global__ __launch_bounds__(256) void pack_w(
    const float* __restrict__ w_def, ushort_t* __restrict__ wPack)
{
    int tid = blockIdx.x * 256 + threadIdx.x;     // 72*16*64 = 73728
    if (tid >= NHS * 16 * 64) return;
    int lane = tid & 63;
    int o = ((tid >> 6) & 15) * 16 + (lane & 15);
    int kbase = (tid >> 10) * 32 + (lane >> 4) * 8;
    union { ushort_t u[8]; short8 v; } pk;
    #pragma unroll
    for (int j = 0; j < 8; ++j) {
        int kidx = kbase + j;
        int c = kidx & 255, tap = kidx >> 8;
        pk.u[j] = f2bf(w_def[((size_t)o * C + c) * 9 + tap]);
    }
    *(short8*)(wPack + (size_t)tid * 8) = pk.v;
}

// ---------------------------------------------------------------------------
// K2: pack w_off into bf16 A-fragment order, M padded 18 -> 32.
// ---------------------------------------------------------------------------
__global__ __launch_bounds__(256) void pack_woffA(
    const float* __restrict__ w_off, ushort_t* __restrict__ wOffA)
{
    int tid = blockIdx.x * 256 + threadIdx.x;     // 72*2*64 = 9216
    if (tid >= NHS * 2 * 64) return;
    int lane = tid & 63;
    int o = ((tid >> 6) & 1) * 16 + (lane & 15);
    int kbase = (tid >> 7) * 32 + (lane >> 4) * 8;
    union { ushort_t u[8]; short8 v; } pk;
    #pragma unroll
    for (int j = 0; j < 8; ++j) {
        int kidx = kbase + j;
        int c = kidx & 255, tap = kidx >> 8;
        pk.u[j] = (o < 18) ? f2bf(w_off[((size_t)o * C + c) * 9 + tap]) : (ushort_t)0;
    }
    *(short8*)(wOffA + (size_t)tid * 8) = pk.v;
}

// ---------------------------------------------------------------------------
// K3: offset conv via MFMA (validated rounds 5-9).  Grid (bl,ho,kg) = 256.
// ---------------------------------------------------------------------------
__global__ __launch_bounds__(256) void offconv_mfma(
    const ushort_t* __restrict__ xtP, const ushort_t* __restrict__ wOffA,
    float* __restrict__ offPart)
{
    int orig = blockIdx.x;
    int r = ((orig & 7) << 5) | (orig >> 3);   // XCD swizzle, 256 blocks
    int bl = r >> 7, ho = (r >> 1) & 63, kg = r & 1;
    int tid = threadIdx.x;
    int lane = tid & 63, wv = tid >> 6;
    int px = wv * 16 + (lane & 15);
    int cseg = (lane >> 4) * 8;

    const ushort_t* xtb = xtP + (size_t)bl * HW * C;
    const short8*   wA  = (const short8*)wOffA;

    f32x4 acc[2];
    acc[0] = (f32x4){0.f, 0.f, 0.f, 0.f};
    acc[1] = (f32x4){0.f, 0.f, 0.f, 0.f};

    int tap0 = kg ? 4 : 0;
    int tap1 = kg ? 9 : 4;

    #pragma unroll 1
    for (int tap = tap0; tap < tap1; ++tap) {
        int ky = tap / 3, kx = tap - ky * 3;
        int y  = ho - 1 + ky;
        int xx = px - 1 + kx;
        bool ok = ((unsigned)y < 64u) && ((unsigned)xx < 64u);
        unsigned msk = ok ? 0xffffffffu : 0u;
        int yc = min(max(y, 0), 63), xc = min(max(xx, 0), 63);
        const ushort_t* srcb = xtb + (size_t)(yc * 64 + xc) * C + cseg;

        #pragma unroll
        for (int cs = 0; cs < 8; ++cs) {
            union { u32x4 u; short8 s; } bv;
            bv.u = *(const u32x4*)(srcb + cs * 32);
            bv.u[0] &= msk; bv.u[1] &= msk; bv.u[2] &= msk; bv.u[3] &= msk;
            int ks = tap * 8 + cs;
            short8 aF0 = wA[(size_t)ks * 128 + lane];
            short8 aF1 = wA[(size_t)ks * 128 + 64 + lane];
            acc[0] = __builtin_amdgcn_mfma_f32_16x16x32_bf16(aF0, bv.s, acc[0], 0, 0, 0);
            acc[1] = __builtin_amdgcn_mfma_f32_16x16x32_bf16(aF1, bv.s, acc[1], 0, 0, 0);
        }
    }

    #pragma unroll
    for (int gt = 0; gt < 2; ++gt) {
        #pragma unroll
        for (int j = 0; j < 4; ++j) {
            int oc = gt * 16 + (lane >> 4) * 4 + j;
            if (oc < 18)
                offPart[(((size_t)kg * 2 + bl) * 18 + oc) * HW + ho * 64 + px] = acc[gt][j];
        }
    }
}

// ---------------------------------------------------------------------------
// K4: bilinear sample + bf16 MFMA GEMM, coalesced loads + IN-REGISTER blend.
// Staging thread (chunk=tid&15, rq=tid>>4) loads runs i*16+rq coalesced;
// those 8 runs are exactly the 4 neighbors of pixels q=rq and q=rq+16, so it
// blends in registers (weights from sWgt, computed with sBase, double-
// buffered by tap parity) and writes the finished B-fragment chunk straight
// to sS.  No raw LDS round-trip.  Loads still issue one full tap ahead and
// stay in flight across non-draining barriers.
// Grid (bl,ho,ohalf,pxh) = 512 blocks x 256 thr (2 blocks/CU).
// ---------------------------------------------------------------------------
__global__ __launch_bounds__(256, 2) void deform_pair(
    const ushort_t* __restrict__ xtP, const float* __restrict__ offPart,
    const ushort_t* __restrict__ wPack, float* __restrict__ out, int pbase)
{
    __shared__ __align__(16) ushort_t sS[2][16][33][8];  // 16.9 KB
    __shared__ float sOff[18][32];                       // 2.3 KB
    __shared__ int   sBase[2][128];                      // run bases (dbuf)
    __shared__ float sWgt[2][32][4];                     // per-px nbr weights

    int orig = blockIdx.x;
    int r = ((orig & 7) << 6) | (orig >> 3);   // XCD swizzle, 512 blocks
    int bl = r >> 8, ho = (r >> 2) & 63, ohalf = (r >> 1) & 1, pxh = r & 1;
    int tid = threadIdx.x;
    int lane = tid & 63, wv = tid >> 6;        // 4 waves
    int chunk = tid & 15, rq = tid >> 4;       // staging identity, rq in [0,16)

    const ushort_t* xtb = xtP + (size_t)bl * HW * C;

    // this row's offsets for our px half (sum of the two K-split partials)
    for (int idx = tid; idx < 18 * 32; idx += 256) {
        int oc = idx >> 5, p2 = idx & 31;
        size_t base = ((size_t)bl * 18 + oc) * HW + ho * 64 + pxh * 32 + p2;
        sOff[oc][p2] = offPart[base] + offPart[(size_t)2 * 18 * HW + base];
    }
    __syncthreads();

    f32x4 acc2[2][2];
    #pragma unroll
    for (int i = 0; i < 2; ++i)
        #pragma unroll
        for (int j = 0; j < 2; ++j) acc2[i][j] = (f32x4){0.f, 0.f, 0.f, 0.f};

    // run bases + per-pixel neighbor weights (validity folded in), dbuf by tap
    auto computeBase = [&](int tap, int buf) {
        if (tid < 128) {
            int n = tid >> 5, q = tid & 31;
            int ky = tap / 3, kx = tap - ky * 3;
            float offy = sOff[2 * tap][q];
            float offx = sOff[2 * tap + 1][q];
            float py  = offy + (float)(ho - 1 + ky);
            float pxf = offx + (float)(pxh * 32 + q - 1 + kx);
            float y0f = floorf(py), x0f = floorf(pxf);
            float wy1 = py - y0f, wx1 = pxf - x0f;
            int y0 = (int)y0f, x0 = (int)x0f;
            int dy = n >> 1, dx = n & 1;
            int yy = y0 + dy, xx = x0 + dx;
            float wn = (dy ? wy1 : (1.f - wy1)) * (dx ? wx1 : (1.f - wx1));
            wn *= (((unsigned)yy < 64u) ? 1.f : 0.f) * (((unsigned)xx < 64u) ? 1.f : 0.f);
            int yc = min(max(yy, 0), 63), xc = min(max(xx, 0), 63);
            sBase[buf][tid] = (yc * 64 + xc) * C;
            sWgt[buf][q][n] = wn;
        }
    };

    auto loadBases = [&](int buf, int* rb) {
        #pragma unroll
        for (int i = 0; i < 8; ++i) rb[i] = sBase[buf][i * 16 + rq];
    };

    // coalesced: 8 x 16B, run i*16+rq, channels sub*128 + chunk*8 ..
    auto issueC = [&](const int* rb, int sub, u32x4* L) {
        #pragma unroll
        for (int i = 0; i < 8; ++i)
            L[i] = *(const u32x4*)(xtb + rb[i] + sub * 128 + chunk * 8);
    };

    // in-register blend: L[2n+pxsel] = neighbor n of pixel rq + pxsel*16
    auto blendDirect = [&](const u32x4* L, const float* w, int p) {
        #pragma unroll
        for (int s = 0; s < 2; ++s) {
            unsigned pk[4];
            #pragma unroll
            for (int j = 0; j < 4; ++j) {
                float f0l = __uint_as_float(L[0 + s][j] << 16);
                float f0h = __uint_as_float(L[0 + s][j] & 0xffff0000u);
                float f1l = __uint_as_float(L[2 + s][j] << 16);
                float f1h = __uint_as_float(L[2 + s][j] & 0xffff0000u);
                float f2l = __uint_as_float(L[4 + s][j] << 16);
                float f2h = __uint_as_float(L[4 + s][j] & 0xffff0000u);
                float f3l = __uint_as_float(L[6 + s][j] << 16);
                float f3h = __uint_as_float(L[6 + s][j] & 0xffff0000u);
                float w0 = w[s * 4 + 0], w1 = w[s * 4 + 1];
                float w2 = w[s * 4 + 2], w3 = w[s * 4 + 3];
                float lo = fmaf(w0, f0l, fmaf(w1, f1l, fmaf(w2, f2l, w3 * f3l)));
                float hi = fmaf(w0, f0h, fmaf(w1, f1h, fmaf(w2, f2h, w3 * f3h)));
                asm("v_cvt_pk_bf16_f32 %0, %1, %2" : "=v"(pk[j]) : "v"(lo), "v"(hi));
            }
            u32x4 wvec = (u32x4){pk[0], pk[1], pk[2], pk[3]};
            *(u32x4*)&sS[p][chunk][rq + s * 16][0] = wvec;
        }
    };

    int gt0 = ohalf * 8 + wv * 2;
    const short8* wpB = (const short8*)wPack;

    auto loadA = [&](int ks4base, short8* A) {   // 8 A-frags for one sub
        #pragma unroll
        for (int h = 0; h < 4; ++h) {
            size_t an = ((size_t)(ks4base + h) * 16 + gt0) * 64 + lane;
            A[2 * h]     = wpB[an];
            A[2 * h + 1] = wpB[an + 64];
        }
    };

    auto mfmaPhase = [&](const short8* A, int p) {
        #pragma unroll
        for (int h = 0; h < 4; ++h) {
            #pragma unroll
            for (int pt = 0; pt < 2; ++pt) {
                short8 bF = *(const short8*)&sS[p][h * 4 + (lane >> 4)][pt * 16 + (lane & 15)][0];
                acc2[0][pt] = __builtin_amdgcn_mfma_f32_16x16x32_bf16(A[2 * h],     bF, acc2[0][pt], 0, 0, 0);
                acc2[1][pt] = __builtin_amdgcn_mfma_f32_16x16x32_bf16(A[2 * h + 1], bF, acc2[1][pt], 0, 0, 0);
            }
        }
    };

    u32x4 LA[8], LB[8];
    short8 A0[8], A1[8];

    // prologue
    computeBase(0, 0);
    block_sync_lds();
    {
        int rb0[8];
        loadBases(0, rb0);
        issueC(rb0, 0, LA);
        issueC(rb0, 1, LB);
    }
    loadA(0, A0);

    int p = 0;
    #pragma unroll 1
    for (int tap = 0; tap < 9; ++tap) {
        // weights for this tap (pixels rq and rq+16), written during tap-1
        float wcur[8];
        *(float4*)&wcur[0] = *(const float4*)&sWgt[tap & 1][rq][0];
        *(float4*)&wcur[4] = *(const float4*)&sWgt[tap & 1][rq + 16][0];
        if (tap < 8) computeBase(tap + 1, (tap + 1) & 1);

        int rb[8];
        // ---- sub 0 ----
        blendDirect(LA, wcur, p);
        block_sync_lds();                               // sS[p] + next bases visible
        if (tap < 8) { loadBases((tap + 1) & 1, rb); issueC(rb, 0, LA); }
        loadA(tap * 8 + 4, A1);
        mfmaPhase(A0, p);
        p ^= 1;
        // ---- sub 1 ----
        blendDirect(LB, wcur, p);
        block_sync_lds();
        if (tap < 8) { issueC(rb, 1, LB); loadA((tap + 1) * 8, A0); }
        mfmaPhase(A1, p);
        p ^= 1;
    }

    // epilogue: D[row=(l>>4)*4+j][col=l&15]
    int b = pbase + bl;
    #pragma unroll
    for (int ot = 0; ot < 2; ++ot) {
        int o = ohalf * 128 + wv * 32 + ot * 16 + (lane >> 4) * 4;
        #pragma unroll
        for (int pt = 0; pt < 2; ++pt) {
            int pxx = pxh * 32 + pt * 16 + (lane & 15);
            #pragma unroll
            for (int j = 0; j < 4; ++j)
                out[(((size_t)b * OCH + (o + j)) * H + ho) * W + pxx] = acc2[ot][pt][j];
        }
    }
}

// ---------------------------------------------------------------------------
extern "C" void kernel_launch(void* const* d_in, const int* in_sizes, int n_in,
                              void* d_out, int out_size, void* d_ws, size_t ws_size,
                              hipStream_t stream)
{
    const float* x     = (const float*)d_in[0];
    const float* w_off = (const float*)d_in[1];
    const float* w_def = (const float*)d_in[2];
    float* out = (float*)d_out;

    // ws: xtPair[4.19MB] | wPack[1.18MB] | wOffA[147KB] | offPart[1.18MB]
    ushort_t* xtP     = (ushort_t*)d_ws;
    ushort_t* wPack   = xtP + (size_t)2 * HW * C;
    ushort_t* wOffA   = wPack + (size_t)NHS * 16 * 64 * 8;
    float*    offPart = (float*)(wOffA + (size_t)NHS * 2 * 64 * 8);

    pack_w<<<(NHS * 16 * 64 + 255) / 256, 256, 0, stream>>>(w_def, wPack);
    pack_woffA<<<(NHS * 2 * 64 + 255) / 256, 256, 0, stream>>>(w_off, wOffA);

    for (int pr = 0; pr < 2; ++pr) {
        transpose_pair<<<512, 256, 0, stream>>>(x, xtP, pr * 2);
        offconv_mfma<<<256, 256, 0, stream>>>(xtP, wOffA, offPart);
        deform_pair<<<512, 256, 0, stream>>>(xtP, offPart, wPack, out, pr * 2);
    }
}